// Round 1
// 273.003 us; speedup vs baseline: 1.0432x; 1.0432x over previous
//
#include <hip/hip_runtime.h>

#define NT    8192   // tokens
#define CIN   4096   // in_channel
#define COUT  4096   // out_channel
#define RK    16     // rank
#define ROWS  16     // tokens per block
#define CHUNK 256    // k per staged chunk
#define NCHUNK (CIN / CHUNK)   // 16
#define ST    260    // LDS row stride (floats): bank = 4*row+k -> 2-way = free

// ---------------------------------------------------------------------------
// Fused: out = (x @ right^T) @ left^T + bias, one kernel, no workspace.
// grid = 512 (16-token row groups), 256 threads (4 waves).
// Phase 1: block owns full K. LDS-staged x/right chunks w/ register prefetch
//          (k1's pattern). Thread = (row, r-quad) x wave = k-quarter:
//          per 4-k step: 1 xs read (broadcast) + 4 rs reads + 16 FMA.
//          Cross-wave reduce in LDS -> t[16][16] stays on-chip.
// Phase 2: k2's body (lf regs, broadcast t reads, float4 stores) x 4 chunks.
// LDS 38.5 KB -> 4 blocks/CU capacity (grid gives 2/CU, 8 waves/CU).
// ---------------------------------------------------------------------------
__global__ __launch_bounds__(256) void fused(const float* __restrict__ x,
                                             const float* __restrict__ rgt,
                                             const float* __restrict__ lft,
                                             const float* __restrict__ bias,
                                             float* __restrict__ out)
{
    __shared__ float xs[ROWS * ST];        // 16640 B
    __shared__ float rs[RK * ST];          // 16640 B
    __shared__ float red[4 * ROWS * 20];   // 5120 B: [wave][row][16 r + pad]
    __shared__ float tl[ROWS * RK];        // 1024 B: t[16][16]

    const int tid  = threadIdx.x;
    const int row0 = blockIdx.x * ROWS;

    // phase-1 compute mapping: wave = k-quarter, lane -> (row, r-quad)
    const int wv   = __builtin_amdgcn_readfirstlane(tid >> 6);
    const int slot = tid & 63;
    const int crow = slot >> 2;        // 0..15
    const int rq   = slot & 3;         // 0..3  (r = rq*4+j)

    // staging mapping: 16 consecutive lanes cover 256 contiguous bytes
    const int srow = tid >> 4;         // 0..15 (x row / right row)
    const int skc  = (tid & 15) * 4;   // 0,4,...,60

    const float* xbase = x + (size_t)row0 * CIN;

    float4 pfx[4], pfr[4];
#pragma unroll
    for (int i = 0; i < 4; ++i) {
        pfx[i] = *(const float4*)&xbase[(size_t)srow * CIN + i * 64 + skc];
        pfr[i] = *(const float4*)&rgt [(size_t)srow * CIN + i * 64 + skc];
    }

    float acc[4] = {0.f, 0.f, 0.f, 0.f};

    for (int c = 0; c < NCHUNK; ++c) {
        // park prefetched chunk (waits vmcnt for these 8 only)
#pragma unroll
        for (int i = 0; i < 4; ++i) {
            float* px = &xs[srow * ST + i * 64 + skc];
            px[0] = pfx[i].x; px[1] = pfx[i].y; px[2] = pfx[i].z; px[3] = pfx[i].w;
            float* pr = &rs[srow * ST + i * 64 + skc];
            pr[0] = pfr[i].x; pr[1] = pfr[i].y; pr[2] = pfr[i].z; pr[3] = pfr[i].w;
        }
        // issue next chunk's loads NOW -> in flight during compute below
        if (c + 1 < NCHUNK) {
            const int kc = (c + 1) * CHUNK;
#pragma unroll
            for (int i = 0; i < 4; ++i) {
                pfx[i] = *(const float4*)&xbase[(size_t)srow * CIN + kc + i * 64 + skc];
                pfr[i] = *(const float4*)&rgt [(size_t)srow * CIN + kc + i * 64 + skc];
            }
        }
        __syncthreads();

        // compute: this wave's 64-k slice of the chunk
        const float* xrow = &xs[crow * ST + wv * 64];
#pragma unroll
        for (int s = 0; s < 16; ++s) {
            const float4 xv = *(const float4*)&xrow[s * 4];
#pragma unroll
            for (int j = 0; j < 4; ++j) {
                const float4 rv =
                    *(const float4*)&rs[(rq * 4 + j) * ST + wv * 64 + s * 4];
                acc[j] += rv.x * xv.x;
                acc[j] += rv.y * xv.y;
                acc[j] += rv.z * xv.z;
                acc[j] += rv.w * xv.w;
            }
        }
        __syncthreads();   // chunk fully consumed before next park
    }

    // ---- cross-wave k-slice reduce -> tl[row][r] (one-time, conflicts ok)
    *(float4*)&red[(wv * ROWS + crow) * 20 + rq * 4] =
        make_float4(acc[0], acc[1], acc[2], acc[3]);
    __syncthreads();
    {
        const int trow = tid >> 4, tr = tid & 15;
        float s = 0.f;
#pragma unroll
        for (int w = 0; w < 4; ++w) s += red[(w * ROWS + trow) * 20 + tr];
        tl[trow * RK + tr] = s;
    }
    __syncthreads();

    // ---- phase 2: out[16][4096] = t @ left^T + bias, 4 column chunks
#pragma unroll 1
    for (int oc = 0; oc < 4; ++oc) {
        const int o0 = oc * 1024 + tid * 4;
        float4 lf[4][4];
#pragma unroll
        for (int oo = 0; oo < 4; ++oo)
#pragma unroll
            for (int q = 0; q < 4; ++q)
                lf[oo][q] = *(const float4*)&lft[(size_t)(o0 + oo) * RK + q * 4];
        const float4 bv = *(const float4*)&bias[o0];
        const float  bvf[4] = {bv.x, bv.y, bv.z, bv.w};

#pragma unroll 4
        for (int rr = 0; rr < ROWS; ++rr) {
            float4 ts[4];
#pragma unroll
            for (int q = 0; q < 4; ++q)
                ts[q] = ((const float4*)tl)[rr * 4 + q];   // uniform -> broadcast

            float res[4];
#pragma unroll
            for (int oo = 0; oo < 4; ++oo) {
                float a = bvf[oo];
#pragma unroll
                for (int q = 0; q < 4; ++q) {
                    a += lf[oo][q].x * ts[q].x;
                    a += lf[oo][q].y * ts[q].y;
                    a += lf[oo][q].z * ts[q].z;
                    a += lf[oo][q].w * ts[q].w;
                }
                res[oo] = a;
            }
            *(float4*)&out[(size_t)(row0 + rr) * COUT + o0] =
                make_float4(res[0], res[1], res[2], res[3]);
        }
    }
}

extern "C" void kernel_launch(void* const* d_in, const int* in_sizes, int n_in,
                              void* d_out, int out_size, void* d_ws, size_t ws_size,
                              hipStream_t stream)
{
    const float* x    = (const float*)d_in[0];
    const float* lft  = (const float*)d_in[1];   // [COUT][RK]
    const float* rgt  = (const float*)d_in[2];   // [RK][CIN]
    const float* bias = (const float*)d_in[3];
    float*       out  = (float*)d_out;

    (void)d_ws; (void)ws_size;                   // workspace no longer used

    fused<<<dim3(NT / ROWS), dim3(256), 0, stream>>>(x, rgt, lft, bias, out);
}